// Round 5
// baseline (287.208 us; speedup 1.0000x reference)
//
#include <hip/hip_runtime.h>

// SESConv via implicit GEMM on bf16 MFMA (gfx950).
// out[b,o,g,h,w] = sum_{rbase valid, ic, xk, yk} Kc[g,rbase,pos,ic,o] * X[b,ic,src(g,rbase), h+xk-2, w+yk-2]
// Kc[...] = sum_f weight[o,ic,rbase,f] * basis[f,g,xk,yk]
// x: (8,16,12,128,128) f32; weight: (16,16,4,9) f32; basis: (9,12,5,5) f32; out: (8,16,12,128,128) f32
//
// R5: revert to R3's 256-thread / 8-rows-per-wave shape (R4's 512-thr split halved
// per-wave ILP and doubled kc load issue -> regression). Replace global_load_lds DMA
// staging with T14 reg-staging: issue 6 global_load_dwordx4 (next slice) BEFORE the
// GEMM, ds_write_b128 x6 AFTER it, then one barrier. R3's 1.02e7 LDS bank-conflict
// cycles came from the async DMA stream landing during the GEMM's ds_reads (R2 with
// ds_write staging measured 0 conflicts on the same read pattern).

#define NRS 12
#define CIN 16
#define COUT 16
#define HW 128
#define IMG (HW*HW)
#define ICSTRIDE (NRS*IMG)        // x stride between input channels (floats)

// fast-path geometry
#define HALO_H 36
#define HALO_W 20
#define ROWB2 640                 // bytes per halo row in LDS: 20 px * 2 halves * 16 B
#define NCHUNK 1440               // 36*20*2 16B-chunks per slice
#define BUFB 23040                // 1440 chunks * 16 B
#define PADW 132
#define PADROWB (PADW*32)         // 4224 B per padded row (132 px * 32 B)

// slow-path (fallback) geometry
#define S_NPIX (HALO_H*HALO_W)    // 720
#define S_HALFB (S_NPIX*16)       // 11520 B per ic-half
#define S_ROWB (HALO_W*16)        // 320

typedef __bf16 bf16x8 __attribute__((ext_vector_type(8)));
typedef float  f32x4  __attribute__((ext_vector_type(4)));

__device__ __forceinline__ unsigned short f2bf(float f) {
    unsigned u = __builtin_bit_cast(unsigned, f);
    u += 0x7fffu + ((u >> 16) & 1u);          // round-nearest-even
    return (unsigned short)(u >> 16);
}

// A-panel: [g(12)][rbase(4)][pp(13)][o(16)][k(32)] bf16, k = possel*16 + ic, pos = 2*pp+possel
// pos==25 -> 0 (pad). 319488 elems = 639 KB.
__global__ void build_kc(const float* __restrict__ wgt, const float* __restrict__ basis,
                         unsigned short* __restrict__ kc) {
    int idx = blockIdx.x * 256 + threadIdx.x;
    const int total = 12 * 4 * 13 * 16 * 32;   // 319488
    if (idx >= total) return;
    int k  = idx & 31;
    int possel = k >> 4, ic = k & 15;
    int o  = (idx >> 5) & 15;
    int t2 = idx >> 9;
    int pp = t2 % 13;
    int gr = t2 / 13;
    int rbase = gr & 3, g = gr >> 2;
    int pos = 2 * pp + possel;
    float s = 0.f;
    if (pos < 25) {
        int xk = pos / 5, yk = pos - 5 * xk;
        #pragma unroll
        for (int f = 0; f < 9; ++f)
            s = fmaf(wgt[((o * CIN + ic) * 4 + rbase) * 9 + f],
                     basis[((f * NRS + g) * 5 + xk) * 5 + yk], s);
    }
    kc[idx] = f2bf(s);
}

// Pre-pass: x (b,ic,s,h,w) f32 -> xbf[b][s][hp 132][wp 132][ic 16] bf16, 2-px zero border.
__global__ void cvt_pad(const float* __restrict__ x, unsigned short* __restrict__ xbf) {
    int idx = blockIdx.x * 256 + threadIdx.x;
    const int total = 8 * 12 * PADW * PADW;    // 1,672,704
    if (idx >= total) return;
    int wp = idx % PADW;
    int t1 = idx / PADW;
    int hp = t1 % PADW;
    int bs = t1 / PADW;                        // b*12 + s
    int s  = bs % 12, bb = bs / 12;
    int h = hp - 2, w = wp - 2;
    bool ok = ((unsigned)h < 128u) && ((unsigned)w < 128u);
    const float* px = x + ((size_t)bb * 192 + s) * IMG + h * HW + w;   // +ic*12*IMG
    unsigned short v[16];
    #pragma unroll
    for (int ic = 0; ic < 16; ++ic) {
        float f = 0.f;
        if (ok) f = px[(size_t)ic * ICSTRIDE];
        v[ic] = f2bf(f);
    }
    uint4 lo, hi;
    lo.x = v[0] | (v[1] << 16);  lo.y = v[2] | (v[3] << 16);
    lo.z = v[4] | (v[5] << 16);  lo.w = v[6] | (v[7] << 16);
    hi.x = v[8] | (v[9] << 16);  hi.y = v[10] | (v[11] << 16);
    hi.z = v[12] | (v[13] << 16); hi.w = v[14] | (v[15] << 16);
    *(uint4*)(xbf + (size_t)idx * 16)     = lo;
    *(uint4*)(xbf + (size_t)idx * 16 + 8) = hi;
}

__global__ __launch_bounds__(256, 2)
void conv_fast(const unsigned short* __restrict__ xbf, const unsigned short* __restrict__ kc,
               float* __restrict__ out) {
    const int b   = blockIdx.z;
    const int r0  = blockIdx.y;                    // 0..3 (r0-column of 3 g's)
    const int th0 = (blockIdx.x >> 3) * 32;        // 4 row-tiles of 32
    const int tw0 = (blockIdx.x & 7) * 16;         // 8 col-tiles of 16

    const int t    = threadIdx.x;
    const int lane = t & 63;
    const int wave = t >> 6;                       // 0..3, owns 8 output rows
    const int n    = lane & 15;        // MFMA N index
    const int q    = lane >> 4;
    const int possel = q >> 1;
    const int half_  = q & 1;

    __shared__ uint4 xs4[(2 * BUFB) / 16];         // 46080 B, double-buffered
    char* xsc = (char*)xs4;

    // staging: 1440 16B chunks, thread t owns chunks t + j*256 (j=0..5, j=5 only t<160).
    // chunk c -> LDS byte c*16; layout [rl(36)][half(2)][cl(20)] 16B chunks.
    const bool tail_ok = (t < NCHUNK - 5 * 256);   // t < 160
    int soff[6];
    #pragma unroll
    for (int j = 0; j < 6; ++j) {
        int c = t + j * 256; if (c >= NCHUNK) c = NCHUNK - 1;   // clamp: in-bounds load, write predicated
        int rl = c / 40, rem = c - rl * 40;
        int hf = rem / 20, cl = rem - hf * 20;
        soff[j] = rl * PADROWB + cl * 32 + hf * 16;
    }

    // B-fragment byte offsets per K-step (within wave's row window)
    int boff[13];
    #pragma unroll
    for (int pp = 0; pp < 13; ++pp) {
        int pos = 2 * pp + possel; if (pos > 24) pos = 24;   // pad tap reads tap 24; A=0 there
        int dx = pos / 5, dy = pos - 5 * dx;
        boff[pp] = dx * ROWB2 + half_ * 320 + (n + dy) * 16;
    }
    const int aoff = n * 32 + q * 8;               // A-frag: o*32 + q*8 (ushort elems)

    f32x4 acc[3][8];
    #pragma unroll
    for (int s0 = 0; s0 < 3; ++s0)
        #pragma unroll
        for (int pg = 0; pg < 8; ++pg) acc[s0][pg] = (f32x4){0.f, 0.f, 0.f, 0.f};

    const char* xb0 = (const char*)xbf;
    const size_t tileoff = ((size_t)th0 * PADW + tw0) * 32;

    uint4 st[6];
    // prologue: load + write slice (i=0, ss=0): sin = r0*3
    {
        const char* sb = xb0 + ((size_t)(b * 12 + r0 * 3) * PADW * PADW) * 32 + tileoff;
        #pragma unroll
        for (int j = 0; j < 6; ++j) st[j] = *(const uint4*)(sb + soff[j]);
        #pragma unroll
        for (int j = 0; j < 5; ++j) *(uint4*)(xsc + (t + j * 256) * 16) = st[j];
        if (tail_ok) *(uint4*)(xsc + (t + 1280) * 16) = st[5];
    }
    __syncthreads();
    int cur = 0;

    #pragma unroll 1
    for (int i = 0; i < 2; ++i) {                  // rolled: acc index never depends on i
        int rr = r0 + i; if (rr >= 4) rr -= 4;
        int rrn = rr + 1; if (rrn >= 4) rrn -= 4;
        #pragma unroll
        for (int ss = 0; ss < 3; ++ss) {           // unrolled: static acc[ss]/acc[ss-1]
            const bool has_next = (i == 0 || ss < 2);
            // ---- issue next slice's global loads into registers (T14 issue-early) ----
            if (has_next) {
                int sin_next = (ss < 2) ? (rr * 3 + ss + 1) : (rrn * 3);
                const char* sb = xb0 + ((size_t)(b * 12 + sin_next) * PADW * PADW) * 32 + tileoff;
                #pragma unroll
                for (int j = 0; j < 6; ++j) st[j] = *(const uint4*)(sb + soff[j]);
            }

            // ---- GEMM over current slice: 13 K-steps x 8 pixel groups, 1-2 users ----
            // user j=0: g = r0*3+ss,   rbase = 2i   -> acc[ss]
            // user j=1: g = r0*3+ss-1, rbase = 2i+1 -> acc[ss-1]   (only ss>0)
            const unsigned short* kc0 = kc + (size_t)((r0 * 3 + ss) * 4 + 2 * i) * (13 * 512);
            const char* wb = xsc + cur * BUFB + wave * 8 * ROWB2;
            if (ss > 0) {
                const unsigned short* kc1 = kc + (size_t)((r0 * 3 + ss - 1) * 4 + 2 * i + 1) * (13 * 512);
                #pragma unroll
                for (int pp = 0; pp < 13; ++pp) {
                    bf16x8 af0 = *(const bf16x8*)(kc0 + pp * 512 + aoff);
                    bf16x8 af1 = *(const bf16x8*)(kc1 + pp * 512 + aoff);
                    const char* wp = wb + boff[pp];
                    #pragma unroll
                    for (int pg = 0; pg < 8; ++pg) {
                        bf16x8 bfv = *(const bf16x8*)(wp + pg * ROWB2);
                        acc[ss][pg]     = __builtin_amdgcn_mfma_f32_16x16x32_bf16(af0, bfv, acc[ss][pg], 0, 0, 0);
                        acc[ss - 1][pg] = __builtin_amdgcn_mfma_f32_16x16x32_bf16(af1, bfv, acc[ss - 1][pg], 0, 0, 0);
                    }
                }
            } else {
                #pragma unroll
                for (int pp = 0; pp < 13; ++pp) {
                    bf16x8 af0 = *(const bf16x8*)(kc0 + pp * 512 + aoff);
                    const char* wp = wb + boff[pp];
                    #pragma unroll
                    for (int pg = 0; pg < 8; ++pg) {
                        bf16x8 bfv = *(const bf16x8*)(wp + pg * ROWB2);
                        acc[ss][pg] = __builtin_amdgcn_mfma_f32_16x16x32_bf16(af0, bfv, acc[ss][pg], 0, 0, 0);
                    }
                }
            }

            // ---- write staged regs to the other buffer (T14 write-late) ----
            if (has_next) {
                char* lb = xsc + (cur ^ 1) * BUFB;
                #pragma unroll
                for (int j = 0; j < 5; ++j) *(uint4*)(lb + (t + j * 256) * 16) = st[j];
                if (tail_ok) *(uint4*)(lb + (t + 1280) * 16) = st[5];
            }
            __syncthreads();
            cur ^= 1;
        }
    }

    // ---- epilogue: D row = o = q*4+reg, col = pixel = n ----
    #pragma unroll
    for (int s0 = 0; s0 < 3; ++s0) {
        const size_t obase = ((size_t)b * COUT * NRS + (r0 * 3 + s0)) * IMG;
        #pragma unroll
        for (int pg = 0; pg < 8; ++pg) {
            int row = th0 + wave * 8 + pg;
            int col = tw0 + n;
            size_t pix = (size_t)row * HW + col;
            #pragma unroll
            for (int r = 0; r < 4; ++r) {
                int o = q * 4 + r;
                out[obase + (size_t)o * NRS * IMG + pix] = acc[s0][pg][r];
            }
        }
    }
}

// Fallback (R2 kernel): used only if workspace can't hold xbf.
__global__ __launch_bounds__(256, 2)
void conv_slow(const float* __restrict__ x, const unsigned short* __restrict__ kc,
               float* __restrict__ out) {
    const int b   = blockIdx.z;
    const int r0  = blockIdx.y;
    const int th0 = (blockIdx.x >> 3) * 32;
    const int tw0 = (blockIdx.x & 7) * 16;

    const int t    = threadIdx.x;
    const int lane = t & 63;
    const int wave = t >> 6;
    const int n    = lane & 15;
    const int q    = lane >> 4;
    const int possel = q >> 1;
    const int half_  = q & 1;

    __shared__ uint4 xs4[(2 * S_HALFB) / 16];
    char* xsc = (char*)xs4;

    int boff[13];
    #pragma unroll
    for (int pp = 0; pp < 13; ++pp) {
        int pos = 2 * pp + possel; if (pos > 24) pos = 24;
        int dx = pos / 5, dy = pos - 5 * dx;
        boff[pp] = half_ * S_HALFB + dx * S_ROWB + (n + dy) * 16;
    }
    const int aoff = n * 32 + q * 8;

    f32x4 acc[3][8];
    #pragma unroll
    for (int s0 = 0; s0 < 3; ++s0)
        #pragma unroll
        for (int pg = 0; pg < 8; ++pg) acc[s0][pg] = (f32x4){0.f, 0.f, 0.f, 0.f};

    #pragma unroll 1
    for (int i = 0; i < 2; ++i) {
        int rr = r0 + i; if (rr >= 4) rr -= 4;
        #pragma unroll
        for (int ss = 0; ss < 3; ++ss) {
            const int sin_ = rr * 3 + ss;
            const float* xb = x + ((size_t)b * CIN * NRS + sin_) * IMG;

            __syncthreads();
            for (int p = t; p < S_NPIX; p += 256) {
                int rl = p / HALO_W, cl = p - rl * HALO_W;
                int hh = th0 + rl - 2, ww = tw0 + cl - 2;
                bool ok = ((unsigned)hh < 128u) && ((unsigned)ww < 128u);
                const float* px = xb + hh * HW + ww;
                unsigned short v[16];
                #pragma unroll
                for (int ic = 0; ic < 16; ++ic) {
                    float f = 0.f;
                    if (ok) f = px[(size_t)ic * ICSTRIDE];
                    v[ic] = f2bf(f);
                }
                uint4 lo, hi;
                lo.x = v[0] | (v[1] << 16);  lo.y = v[2] | (v[3] << 16);
                lo.z = v[4] | (v[5] << 16);  lo.w = v[6] | (v[7] << 16);
                hi.x = v[8] | (v[9] << 16);  hi.y = v[10] | (v[11] << 16);
                hi.z = v[12] | (v[13] << 16); hi.w = v[14] | (v[15] << 16);
                *(uint4*)(xsc + p * 16)           = lo;
                *(uint4*)(xsc + S_HALFB + p * 16) = hi;
            }
            __syncthreads();

            const unsigned short* kc0 = kc + (size_t)((r0 * 3 + ss) * 4 + 2 * i) * (13 * 512);
            const unsigned short* kc1 = kc + (size_t)((r0 * 3 + ss - 1) * 4 + 2 * i + 1) * (13 * 512);
            const char* wb = xsc + wave * 8 * S_ROWB;
            #pragma unroll
            for (int pp = 0; pp < 13; ++pp) {
                bf16x8 af0 = *(const bf16x8*)(kc0 + pp * 512 + aoff);
                bf16x8 af1;
                if (ss > 0) af1 = *(const bf16x8*)(kc1 + pp * 512 + aoff);
                const char* wp = wb + boff[pp];
                #pragma unroll
                for (int pg = 0; pg < 8; ++pg) {
                    bf16x8 bfv = *(const bf16x8*)(wp + pg * S_ROWB);
                    acc[ss][pg] = __builtin_amdgcn_mfma_f32_16x16x32_bf16(af0, bfv, acc[ss][pg], 0, 0, 0);
                    if (ss > 0)
                        acc[ss - 1][pg] = __builtin_amdgcn_mfma_f32_16x16x32_bf16(af1, bfv, acc[ss - 1][pg], 0, 0, 0);
                }
            }
        }
    }

    #pragma unroll
    for (int s0 = 0; s0 < 3; ++s0) {
        const size_t obase = ((size_t)b * COUT * NRS + (r0 * 3 + s0)) * IMG;
        #pragma unroll
        for (int pg = 0; pg < 8; ++pg) {
            int row = th0 + wave * 8 + pg;
            int col = tw0 + n;
            size_t pix = (size_t)row * HW + col;
            #pragma unroll
            for (int r = 0; r < 4; ++r) {
                int o = q * 4 + r;
                out[obase + (size_t)o * NRS * IMG + pix] = acc[s0][pg][r];
            }
        }
    }
}

extern "C" void kernel_launch(void* const* d_in, const int* in_sizes, int n_in,
                              void* d_out, int out_size, void* d_ws, size_t ws_size,
                              hipStream_t stream) {
    const float* x      = (const float*)d_in[0];
    const float* weight = (const float*)d_in[1];
    const float* basis  = (const float*)d_in[2];
    float* out = (float*)d_out;
    unsigned short* kc = (unsigned short*)d_ws;            // 639 KB

    build_kc<<<dim3((12 * 4 * 13 * 16 * 32 + 255) / 256), dim3(256), 0, stream>>>(weight, basis, kc);

    const size_t xbf_off = 655360;                         // 640 KB, 16B-aligned
    const size_t xbf_bytes = (size_t)8 * 12 * PADW * PADW * 32;   // 53.5 MB
    if (ws_size >= xbf_off + xbf_bytes) {
        unsigned short* xbf = (unsigned short*)((char*)d_ws + xbf_off);
        cvt_pad<<<dim3((8 * 12 * PADW * PADW + 255) / 256), dim3(256), 0, stream>>>(x, xbf);
        conv_fast<<<dim3(32, 4, 8), dim3(256), 0, stream>>>(xbf, kc, out);
    } else {
        conv_slow<<<dim3(32, 4, 8), dim3(256), 0, stream>>>(x, kc, out);
    }
}

// Round 6
// 254.684 us; speedup vs baseline: 1.1277x; 1.1277x over previous
//
#include <hip/hip_runtime.h>

// SESConv via implicit GEMM on bf16 MFMA (gfx950).
// out[b,o,g,h,w] = sum_{rbase valid, ic, xk, yk} Kc[g,rbase,pos,ic,o] * X[b,ic,src(g,rbase), h+xk-2, w+yk-2]
// Kc[...] = sum_f weight[o,ic,rbase,f] * basis[f,g,xk,yk]
// x: (8,16,12,128,128) f32; weight: (16,16,4,9) f32; basis: (9,12,5,5) f32; out: (8,16,12,128,128) f32
//
// R6: R3 (best: 85.9us) with ONE change: the DMA chunk->global permutation is altered
// so the LDS layout becomes R2's [half(2)][row(36) 320B][col(20)] — the layout whose
// read pattern measured 0 bank conflicts (R2), vs 1.022e7 for R3's [rl][half][cl]
// 640B-row layout. R5 proved the conflicts are read-side layout (identical 1.022e7
// with totally different staging) and that reg-staging spills (WRITE 217MB) — so keep
// DMA staging (global source addr is per-lane; LDS dest stays linear).

#define NRS 12
#define CIN 16
#define COUT 16
#define HW 128
#define IMG (HW*HW)
#define ICSTRIDE (NRS*IMG)        // x stride between input channels (floats)

// fast-path geometry: LDS slice = [half(2)][rl(36)][cl(20)] 16B chunks, rows 320B
#define HALO_H 36
#define HALO_W 20
#define ROWB 320                  // bytes per halo row per half (20 px * 16 B)
#define HALFB 11520               // 720 chunks * 16 B per ic-half
#define NCHUNK 1440               // 36*20*2 16B-chunks per slice
#define BUFB 24576                // 1536 chunks * 16 B (4 waves * 6 * 64); 96 pad chunks
#define PADW 132
#define PADROWB (PADW*32)         // 4224 B per padded row (132 px * 32 B)

typedef __bf16 bf16x8 __attribute__((ext_vector_type(8)));
typedef float  f32x4  __attribute__((ext_vector_type(4)));

__device__ __forceinline__ unsigned short f2bf(float f) {
    unsigned u = __builtin_bit_cast(unsigned, f);
    u += 0x7fffu + ((u >> 16) & 1u);          // round-nearest-even
    return (unsigned short)(u >> 16);
}

// A-panel: [g(12)][rbase(4)][pp(13)][o(16)][k(32)] bf16, k = possel*16 + ic, pos = 2*pp+possel
// pos==25 -> 0 (pad). 319488 elems = 639 KB.
__global__ void build_kc(const float* __restrict__ wgt, const float* __restrict__ basis,
                         unsigned short* __restrict__ kc) {
    int idx = blockIdx.x * 256 + threadIdx.x;
    const int total = 12 * 4 * 13 * 16 * 32;   // 319488
    if (idx >= total) return;
    int k  = idx & 31;
    int possel = k >> 4, ic = k & 15;
    int o  = (idx >> 5) & 15;
    int t2 = idx >> 9;
    int pp = t2 % 13;
    int gr = t2 / 13;
    int rbase = gr & 3, g = gr >> 2;
    int pos = 2 * pp + possel;
    float s = 0.f;
    if (pos < 25) {
        int xk = pos / 5, yk = pos - 5 * xk;
        #pragma unroll
        for (int f = 0; f < 9; ++f)
            s = fmaf(wgt[((o * CIN + ic) * 4 + rbase) * 9 + f],
                     basis[((f * NRS + g) * 5 + xk) * 5 + yk], s);
    }
    kc[idx] = f2bf(s);
}

// Pre-pass: x (b,ic,s,h,w) f32 -> xbf[b][s][hp 132][wp 132][ic 16] bf16, 2-px zero border.
__global__ void cvt_pad(const float* __restrict__ x, unsigned short* __restrict__ xbf) {
    int idx = blockIdx.x * 256 + threadIdx.x;
    const int total = 8 * 12 * PADW * PADW;    // 1,672,704
    if (idx >= total) return;
    int wp = idx % PADW;
    int t1 = idx / PADW;
    int hp = t1 % PADW;
    int bs = t1 / PADW;                        // b*12 + s
    int s  = bs % 12, bb = bs / 12;
    int h = hp - 2, w = wp - 2;
    bool ok = ((unsigned)h < 128u) && ((unsigned)w < 128u);
    const float* px = x + ((size_t)bb * 192 + s) * IMG + h * HW + w;   // +ic*12*IMG
    unsigned short v[16];
    #pragma unroll
    for (int ic = 0; ic < 16; ++ic) {
        float f = 0.f;
        if (ok) f = px[(size_t)ic * ICSTRIDE];
        v[ic] = f2bf(f);
    }
    uint4 lo, hi;
    lo.x = v[0] | (v[1] << 16);  lo.y = v[2] | (v[3] << 16);
    lo.z = v[4] | (v[5] << 16);  lo.w = v[6] | (v[7] << 16);
    hi.x = v[8] | (v[9] << 16);  hi.y = v[10] | (v[11] << 16);
    hi.z = v[12] | (v[13] << 16); hi.w = v[14] | (v[15] << 16);
    *(uint4*)(xbf + (size_t)idx * 16)     = lo;
    *(uint4*)(xbf + (size_t)idx * 16 + 8) = hi;
}

__global__ __launch_bounds__(256, 2)
void conv_fast(const unsigned short* __restrict__ xbf, const unsigned short* __restrict__ kc,
               float* __restrict__ out) {
    const int b   = blockIdx.z;
    const int r0  = blockIdx.y;                    // 0..3 (r0-column of 3 g's)
    const int th0 = (blockIdx.x >> 3) * 32;        // 4 row-tiles of 32
    const int tw0 = (blockIdx.x & 7) * 16;         // 8 col-tiles of 16

    const int t    = threadIdx.x;
    const int lane = t & 63;
    const int wave = t >> 6;                       // 0..3, owns 8 output rows
    const int n    = lane & 15;        // MFMA N index
    const int q    = lane >> 4;
    const int possel = q >> 1;
    const int half_  = q & 1;

    __shared__ uint4 xs4[(2 * BUFB) / 16];         // 49152 B, double-buffered
    char* xsc = (char*)xs4;

    // staging: chunk c (LDS byte c*16) <- global (half, rl, cl):
    //   half = c/720, p = c%720, rl = p/20, cl = p%20  -> src rl*PADROWB + cl*32 + half*16.
    // This reproduces R2's zero-conflict read layout; LDS dest stays DMA-linear.
    int soff[6];
    #pragma unroll
    for (int j = 0; j < 6; ++j) {
        int c = wave * 384 + j * 64 + lane;
        if (c < NCHUNK) {
            int hf = c / 720, p = c - hf * 720;
            int rl = p / 20, cl = p - rl * 20;
            soff[j] = rl * PADROWB + cl * 32 + hf * 16;
        } else soff[j] = 0;                        // pad chunk: in-bounds read -> LDS pad region
    }

    // B-fragment byte offsets per K-step (R2's proven-conflict-free pattern)
    int boff[13];
    #pragma unroll
    for (int pp = 0; pp < 13; ++pp) {
        int pos = 2 * pp + possel; if (pos > 24) pos = 24;   // pad tap reads tap 24; A=0 there
        int dx = pos / 5, dy = pos - 5 * dx;
        boff[pp] = half_ * HALFB + dx * ROWB + (n + dy) * 16;
    }
    const int aoff = n * 32 + q * 8;               // A-frag: o*32 + q*8 (ushort elems)

    f32x4 acc[3][8];
    #pragma unroll
    for (int s0 = 0; s0 < 3; ++s0)
        #pragma unroll
        for (int pg = 0; pg < 8; ++pg) acc[s0][pg] = (f32x4){0.f, 0.f, 0.f, 0.f};

    const char* xb0 = (const char*)xbf;
    const size_t tileoff = ((size_t)th0 * PADW + tw0) * 32;

    // prologue: stage slice (i=0, ss=0): sin = r0*3
    {
        const char* sb = xb0 + ((size_t)(b * 12 + r0 * 3) * PADW * PADW) * 32 + tileoff;
        char* lb = xsc + wave * 6144;
        #pragma unroll
        for (int j = 0; j < 6; ++j)
            __builtin_amdgcn_global_load_lds(
                (const __attribute__((address_space(1))) void*)(sb + soff[j]),
                (__attribute__((address_space(3))) void*)(lb + j * 1024), 16, 0, 0);
    }
    __syncthreads();
    int cur = 0;

    #pragma unroll 1
    for (int i = 0; i < 2; ++i) {                  // rolled: acc index never depends on i
        int rr = r0 + i; if (rr >= 4) rr -= 4;
        int rrn = rr + 1; if (rrn >= 4) rrn -= 4;
        #pragma unroll
        for (int ss = 0; ss < 3; ++ss) {           // unrolled: static acc[ss]/acc[ss-1]
            // ---- issue async stage of next slice into buf[cur^1] ----
            if (i == 0 || ss < 2) {
                int sin_next = (ss < 2) ? (rr * 3 + ss + 1) : (rrn * 3);
                const char* sb = xb0 + ((size_t)(b * 12 + sin_next) * PADW * PADW) * 32 + tileoff;
                char* lb = xsc + (cur ^ 1) * BUFB + wave * 6144;
                #pragma unroll
                for (int j = 0; j < 6; ++j)
                    __builtin_amdgcn_global_load_lds(
                        (const __attribute__((address_space(1))) void*)(sb + soff[j]),
                        (__attribute__((address_space(3))) void*)(lb + j * 1024), 16, 0, 0);
            }

            // ---- GEMM over current slice: 13 K-steps x 8 pixel groups, 1-2 users ----
            // user j=0: g = r0*3+ss,   rbase = 2i   -> acc[ss]
            // user j=1: g = r0*3+ss-1, rbase = 2i+1 -> acc[ss-1]   (only ss>0)
            const unsigned short* kc0 = kc + (size_t)((r0 * 3 + ss) * 4 + 2 * i) * (13 * 512);
            const char* wb = xsc + cur * BUFB + wave * 8 * ROWB;
            if (ss > 0) {
                const unsigned short* kc1 = kc + (size_t)((r0 * 3 + ss - 1) * 4 + 2 * i + 1) * (13 * 512);
                #pragma unroll
                for (int pp = 0; pp < 13; ++pp) {
                    bf16x8 af0 = *(const bf16x8*)(kc0 + pp * 512 + aoff);
                    bf16x8 af1 = *(const bf16x8*)(kc1 + pp * 512 + aoff);
                    const char* wp = wb + boff[pp];
                    #pragma unroll
                    for (int pg = 0; pg < 8; ++pg) {
                        bf16x8 bfv = *(const bf16x8*)(wp + pg * ROWB);
                        acc[ss][pg]     = __builtin_amdgcn_mfma_f32_16x16x32_bf16(af0, bfv, acc[ss][pg], 0, 0, 0);
                        acc[ss - 1][pg] = __builtin_amdgcn_mfma_f32_16x16x32_bf16(af1, bfv, acc[ss - 1][pg], 0, 0, 0);
                    }
                }
            } else {
                #pragma unroll
                for (int pp = 0; pp < 13; ++pp) {
                    bf16x8 af0 = *(const bf16x8*)(kc0 + pp * 512 + aoff);
                    const char* wp = wb + boff[pp];
                    #pragma unroll
                    for (int pg = 0; pg < 8; ++pg) {
                        bf16x8 bfv = *(const bf16x8*)(wp + pg * ROWB);
                        acc[ss][pg] = __builtin_amdgcn_mfma_f32_16x16x32_bf16(af0, bfv, acc[ss][pg], 0, 0, 0);
                    }
                }
            }
            __syncthreads();       // drains vmcnt (stage landed) + lgkm; all waves' stages visible
            cur ^= 1;
        }
    }

    // ---- epilogue: D row = o = q*4+reg, col = pixel = n ----
    #pragma unroll
    for (int s0 = 0; s0 < 3; ++s0) {
        const size_t obase = ((size_t)b * COUT * NRS + (r0 * 3 + s0)) * IMG;
        #pragma unroll
        for (int pg = 0; pg < 8; ++pg) {
            int row = th0 + wave * 8 + pg;
            int col = tw0 + n;
            size_t pix = (size_t)row * HW + col;
            #pragma unroll
            for (int r = 0; r < 4; ++r) {
                int o = q * 4 + r;
                out[obase + (size_t)o * NRS * IMG + pix] = acc[s0][pg][r];
            }
        }
    }
}

// Fallback: direct-from-x version (R2 structure), used only if workspace can't hold xbf.
__global__ __launch_bounds__(256, 2)
void conv_slow(const float* __restrict__ x, const unsigned short* __restrict__ kc,
               float* __restrict__ out) {
    const int b   = blockIdx.z;
    const int r0  = blockIdx.y;
    const int th0 = (blockIdx.x >> 3) * 32;
    const int tw0 = (blockIdx.x & 7) * 16;

    const int t    = threadIdx.x;
    const int lane = t & 63;
    const int wave = t >> 6;
    const int n    = lane & 15;
    const int q    = lane >> 4;
    const int possel = q >> 1;
    const int half_  = q & 1;

    __shared__ uint4 xs4[(2 * HALFB) / 16];
    char* xsc = (char*)xs4;

    int boff[13];
    #pragma unroll
    for (int pp = 0; pp < 13; ++pp) {
        int pos = 2 * pp + possel; if (pos > 24) pos = 24;
        int dx = pos / 5, dy = pos - 5 * dx;
        boff[pp] = half_ * HALFB + dx * ROWB + (n + dy) * 16;
    }
    const int aoff = n * 32 + q * 8;

    f32x4 acc[3][8];
    #pragma unroll
    for (int s0 = 0; s0 < 3; ++s0)
        #pragma unroll
        for (int pg = 0; pg < 8; ++pg) acc[s0][pg] = (f32x4){0.f, 0.f, 0.f, 0.f};

    #pragma unroll 1
    for (int i = 0; i < 2; ++i) {
        int rr = r0 + i; if (rr >= 4) rr -= 4;
        #pragma unroll
        for (int ss = 0; ss < 3; ++ss) {
            const int sin_ = rr * 3 + ss;
            const float* xb = x + ((size_t)b * CIN * NRS + sin_) * IMG;

            __syncthreads();
            for (int p = t; p < 720; p += 256) {
                int rl = p / HALO_W, cl = p - rl * HALO_W;
                int hh = th0 + rl - 2, ww = tw0 + cl - 2;
                bool ok = ((unsigned)hh < 128u) && ((unsigned)ww < 128u);
                const float* px = xb + hh * HW + ww;
                unsigned short v[16];
                #pragma unroll
                for (int ic = 0; ic < 16; ++ic) {
                    float f = 0.f;
                    if (ok) f = px[(size_t)ic * ICSTRIDE];
                    v[ic] = f2bf(f);
                }
                uint4 lo, hi;
                lo.x = v[0] | (v[1] << 16);  lo.y = v[2] | (v[3] << 16);
                lo.z = v[4] | (v[5] << 16);  lo.w = v[6] | (v[7] << 16);
                hi.x = v[8] | (v[9] << 16);  hi.y = v[10] | (v[11] << 16);
                hi.z = v[12] | (v[13] << 16); hi.w = v[14] | (v[15] << 16);
                *(uint4*)(xsc + p * 16)         = lo;
                *(uint4*)(xsc + HALFB + p * 16) = hi;
            }
            __syncthreads();

            const unsigned short* kc0 = kc + (size_t)((r0 * 3 + ss) * 4 + 2 * i) * (13 * 512);
            const unsigned short* kc1 = kc + (size_t)((r0 * 3 + ss - 1) * 4 + 2 * i + 1) * (13 * 512);
            const char* wb = xsc + wave * 8 * ROWB;
            #pragma unroll
            for (int pp = 0; pp < 13; ++pp) {
                bf16x8 af0 = *(const bf16x8*)(kc0 + pp * 512 + aoff);
                bf16x8 af1;
                if (ss > 0) af1 = *(const bf16x8*)(kc1 + pp * 512 + aoff);
                const char* wp = wb + boff[pp];
                #pragma unroll
                for (int pg = 0; pg < 8; ++pg) {
                    bf16x8 bfv = *(const bf16x8*)(wp + pg * ROWB);
                    acc[ss][pg] = __builtin_amdgcn_mfma_f32_16x16x32_bf16(af0, bfv, acc[ss][pg], 0, 0, 0);
                    if (ss > 0)
                        acc[ss - 1][pg] = __builtin_amdgcn_mfma_f32_16x16x32_bf16(af1, bfv, acc[ss - 1][pg], 0, 0, 0);
                }
            }
        }
    }

    #pragma unroll
    for (int s0 = 0; s0 < 3; ++s0) {
        const size_t obase = ((size_t)b * COUT * NRS + (r0 * 3 + s0)) * IMG;
        #pragma unroll
        for (int pg = 0; pg < 8; ++pg) {
            int row = th0 + wave * 8 + pg;
            int col = tw0 + n;
            size_t pix = (size_t)row * HW + col;
            #pragma unroll
            for (int r = 0; r < 4; ++r) {
                int o = q * 4 + r;
                out[obase + (size_t)o * NRS * IMG + pix] = acc[s0][pg][r];
            }
        }
    }
}

extern "C" void kernel_launch(void* const* d_in, const int* in_sizes, int n_in,
                              void* d_out, int out_size, void* d_ws, size_t ws_size,
                              hipStream_t stream) {
    const float* x      = (const float*)d_in[0];
    const float* weight = (const float*)d_in[1];
    const float* basis  = (const float*)d_in[2];
    float* out = (float*)d_out;
    unsigned short* kc = (unsigned short*)d_ws;            // 639 KB

    build_kc<<<dim3((12 * 4 * 13 * 16 * 32 + 255) / 256), dim3(256), 0, stream>>>(weight, basis, kc);

    const size_t xbf_off = 655360;                         // 640 KB, 16B-aligned
    const size_t xbf_bytes = (size_t)8 * 12 * PADW * PADW * 32;   // 53.5 MB
    if (ws_size >= xbf_off + xbf_bytes) {
        unsigned short* xbf = (unsigned short*)((char*)d_ws + xbf_off);
        cvt_pad<<<dim3((8 * 12 * PADW * PADW + 255) / 256), dim3(256), 0, stream>>>(x, xbf);
        conv_fast<<<dim3(32, 4, 8), dim3(256), 0, stream>>>(xbf, kc, out);
    } else {
        conv_slow<<<dim3(32, 4, 8), dim3(256), 0, stream>>>(x, kc, out);
    }
}